// Round 5
// baseline (739.618 us; speedup 1.0000x reference)
//
#include <hip/hip_runtime.h>
#include <cstdint>
#include <cstddef>

// MultiResHashGrid encode: 1e6 points, 16 levels, 2 feats/level, 2^19 hashmap.
// Output per point: [x,y,z, f(l0,0),f(l0,1), ..., f(l15,0),f(l15,1)] = 35 f32.
//
// R6: single-kernel direct store (pass2 eliminated).
//   Evidence ladder: pass1 time is invariant to FETCH (466/400/424/361 MB all
//   ~349-357us) and to coalesced-load count (R4 -17% instrs -> -2%), but
//   scales with per-lane gather bytes (R3 16B/lane -> +33%). Model: VMEM
//   divergent path processes ~8B/lane/cycle; 8x8B gathers are the irreducible
//   floor (~273us ideal, 349us observed). So pass1 can't improve; the
//   recoverable cost is pass2's 183us transpose.
//   Change: keep the level-major grid (per-XCD table locality), store the two
//   features directly into the point-major out row (scattered 2x dword
//   stores, 4B-aligned; stores need no return data -> bounded ~+11% on the
//   write path). Level-0 blocks also write xyz. No workspace, one dispatch.
//   Predict: total 552 -> ~360-400us, WRITE_SIZE ~140MB, single dispatch.

#define NPTS     1000000
#define NLEV     16
#define TBL_ENT  524288      // 2^19 entries per level
#define BLK      256
#define OUT_PP   35          // floats per point
#define CHUNKS   ((NPTS + BLK - 1) / BLK)   // 3907

// r:  16  22  30  42  58  80  111  153  212  294  406  561  776  1072 1482 2048
// hs: min(r^3, 2^19)
constexpr float    cRes[NLEV] = {16.f, 22.f, 30.f, 42.f, 58.f, 80.f, 111.f, 153.f,
                                 212.f, 294.f, 406.f, 561.f, 776.f, 1072.f, 1482.f, 2048.f};
constexpr uint32_t cHS[NLEV]  = {4096u, 10648u, 27000u, 74088u, 195112u, 512000u,
                                 524288u, 524288u, 524288u, 524288u, 524288u,
                                 524288u, 524288u, 524288u, 524288u, 524288u};

// ---------------- per-level gather (R2 form), compile-time level params ----------------

template<int L>
__device__ __forceinline__ void do_level(float px, float py, float pz,
                                         const float* __restrict__ tables,
                                         float& f0, float& f1)
{
    constexpr float    r  = cRes[L];
    constexpr uint32_t hs = cHS[L];
    const float2* __restrict__ tbl =
        reinterpret_cast<const float2*>(tables) + (size_t)L * TBL_ENT;

    const float xs = px * r, ys = py * r, zs = pz * r;
    const int xi = (int)xs, yi = (int)ys, zi = (int)zs;
    const float xf = xs - (float)xi, yf = ys - (float)yi, zf = zs - (float)zi;

    const uint32_t hx0 = (uint32_t)xi;
    const uint32_t hx1 = hx0 + 1u;
    const uint32_t hy0 = (uint32_t)yi * 2654435761u;
    const uint32_t hy1 = hy0 + 2654435761u;
    const uint32_t hz0 = (uint32_t)zi * 805459861u;
    const uint32_t hz1 = hz0 + 805459861u;

    const float wx0 = 1.f - xf, wx1 = xf;
    const float wy0 = 1.f - yf, wy1 = yf;
    const float wz0 = 1.f - zf, wz1 = zf;

    uint32_t hid[8];
    float    w[8];
    #pragma unroll
    for (int c = 0; c < 8; ++c) {
        const uint32_t hxc = (c & 1) ? hx1 : hx0;
        const uint32_t hyc = (c & 2) ? hy1 : hy0;
        const uint32_t hzc = (c & 4) ? hz1 : hz0;
        hid[c] = (hxc ^ hyc ^ hzc) % hs;   // hs compile-time: AND or magic-mul
        const float wxc = (c & 1) ? wx1 : wx0;
        const float wyc = (c & 2) ? wy1 : wy0;
        const float wzc = (c & 4) ? wz1 : wz0;
        w[c] = wxc * wyc * wzc;
    }

    float2 v[8];
    #pragma unroll
    for (int c = 0; c < 8; ++c) v[c] = tbl[hid[c]];

    f0 = 0.f; f1 = 0.f;
    #pragma unroll
    for (int c = 0; c < 8; ++c) {
        f0 = fmaf(w[c], v[c].x, f0);
        f1 = fmaf(w[c], v[c].y, f1);
    }
}

// ---------------- single kernel: level-major gather, direct point-major store ----------------

__global__ __launch_bounds__(BLK) void hashgrid_direct(
    const float* __restrict__ x,
    const float* __restrict__ tables,
    float* __restrict__ out)
{
    const int b = blockIdx.x;
    const int l = b / CHUNKS;          // level (block-uniform)
    const int c = b - l * CHUNKS;      // point chunk
    const int i = c * BLK + threadIdx.x;
    if (i >= NPTS) return;

    // nt loads: no L1/L2 allocate; the active 4MB table keeps the XCD L2
    const float px = __builtin_nontemporal_load(&x[3 * i + 0]);
    const float py = __builtin_nontemporal_load(&x[3 * i + 1]);
    const float pz = __builtin_nontemporal_load(&x[3 * i + 2]);

    float f0, f1;
    switch (l) {
        case 0:  do_level<0 >(px, py, pz, tables, f0, f1); break;
        case 1:  do_level<1 >(px, py, pz, tables, f0, f1); break;
        case 2:  do_level<2 >(px, py, pz, tables, f0, f1); break;
        case 3:  do_level<3 >(px, py, pz, tables, f0, f1); break;
        case 4:  do_level<4 >(px, py, pz, tables, f0, f1); break;
        case 5:  do_level<5 >(px, py, pz, tables, f0, f1); break;
        case 6:  do_level<6 >(px, py, pz, tables, f0, f1); break;
        case 7:  do_level<7 >(px, py, pz, tables, f0, f1); break;
        case 8:  do_level<8 >(px, py, pz, tables, f0, f1); break;
        case 9:  do_level<9 >(px, py, pz, tables, f0, f1); break;
        case 10: do_level<10>(px, py, pz, tables, f0, f1); break;
        case 11: do_level<11>(px, py, pz, tables, f0, f1); break;
        case 12: do_level<12>(px, py, pz, tables, f0, f1); break;
        case 13: do_level<13>(px, py, pz, tables, f0, f1); break;
        case 14: do_level<14>(px, py, pz, tables, f0, f1); break;
        default: do_level<15>(px, py, pz, tables, f0, f1); break;
    }

    // direct point-major store: two 4B-aligned dword stores into the out row.
    // Scattered (140B stride) but stores need no return data; different-level
    // blocks write disjoint bytes of shared lines (L2 byte-enable merge).
    float* __restrict__ o = out + (size_t)i * OUT_PP;
    o[3 + 2 * l]  = f0;
    o[4 + 2 * l]  = f1;
    if (l == 0) {           // block-uniform branch: level-0 blocks carry xyz
        o[0] = px;
        o[1] = py;
        o[2] = pz;
    }
}

// ---------------- Fallback (point-major single kernel; not used on this shape) ----------------

__global__ __launch_bounds__(BLK) void hashgrid_fused(
    const float* __restrict__ x,
    const float* __restrict__ tables,
    float* __restrict__ out)
{
    __shared__ float smem[BLK * OUT_PP];

    const int t = threadIdx.x;
    const int i = blockIdx.x * BLK + t;
    const bool active = (i < NPTS);

    float px = 0.f, py = 0.f, pz = 0.f;
    if (active) {
        px = x[3 * i + 0];
        py = x[3 * i + 1];
        pz = x[3 * i + 2];
    }
    smem[t * OUT_PP + 0] = px;
    smem[t * OUT_PP + 1] = py;
    smem[t * OUT_PP + 2] = pz;

    float f0, f1;
    #pragma unroll
    for (int l = 0; l < NLEV; ++l) {
        switch (l) {
            case 0:  do_level<0 >(px, py, pz, tables, f0, f1); break;
            case 1:  do_level<1 >(px, py, pz, tables, f0, f1); break;
            case 2:  do_level<2 >(px, py, pz, tables, f0, f1); break;
            case 3:  do_level<3 >(px, py, pz, tables, f0, f1); break;
            case 4:  do_level<4 >(px, py, pz, tables, f0, f1); break;
            case 5:  do_level<5 >(px, py, pz, tables, f0, f1); break;
            case 6:  do_level<6 >(px, py, pz, tables, f0, f1); break;
            case 7:  do_level<7 >(px, py, pz, tables, f0, f1); break;
            case 8:  do_level<8 >(px, py, pz, tables, f0, f1); break;
            case 9:  do_level<9 >(px, py, pz, tables, f0, f1); break;
            case 10: do_level<10>(px, py, pz, tables, f0, f1); break;
            case 11: do_level<11>(px, py, pz, tables, f0, f1); break;
            case 12: do_level<12>(px, py, pz, tables, f0, f1); break;
            case 13: do_level<13>(px, py, pz, tables, f0, f1); break;
            case 14: do_level<14>(px, py, pz, tables, f0, f1); break;
            default: do_level<15>(px, py, pz, tables, f0, f1); break;
        }
        smem[t * OUT_PP + 3 + 2 * l]     = f0;
        smem[t * OUT_PP + 3 + 2 * l + 1] = f1;
    }

    __syncthreads();

    const size_t gbase = (size_t)blockIdx.x * (BLK * OUT_PP);
    const long long remain = (long long)NPTS * OUT_PP - (long long)gbase;
    const int n4 = (int)((remain < (long long)(BLK * OUT_PP) ? remain : (long long)(BLK * OUT_PP)) / 4);
    const float4* __restrict__ s4 = reinterpret_cast<const float4*>(smem);
    float4* __restrict__ o4 = reinterpret_cast<float4*>(out + gbase);
    for (int j = t; j < n4; j += BLK) o4[j] = s4[j];
}

extern "C" void kernel_launch(void* const* d_in, const int* in_sizes, int n_in,
                              void* d_out, int out_size, void* d_ws, size_t ws_size,
                              hipStream_t stream)
{
    const float* x      = (const float*)d_in[0];   // (1e6, 3) f32
    const float* tables = (const float*)d_in[1];   // (16, 2^19, 2) f32
    float* out          = (float*)d_out;           // (1e6, 35) f32

    // Single dispatch, no workspace needed.
    hashgrid_direct<<<NLEV * CHUNKS, BLK, 0, stream>>>(x, tables, out);
    (void)d_ws; (void)ws_size;
}

// Round 6
// 552.157 us; speedup vs baseline: 1.3395x; 1.3395x over previous
//
#include <hip/hip_runtime.h>
#include <cstdint>
#include <cstddef>

// MultiResHashGrid encode: 1e6 points, 16 levels, 2 feats/level, 2^19 hashmap.
// Output per point: [x,y,z, f(l0,0),f(l0,1), ..., f(l15,0),f(l15,1)] = 35 f32.
//
// R7: two-pass, latency-tolerant pass2.
//   Evidence ladder: pass1 (~349us) is invariant to FETCH 361-466MB and to
//   coalesced-instr count; gather request path is the floor. R6 proved
//   scattered partial-line stores cause RMW amplification (WRITE 125->574MB,
//   FETCH ->1GB): transpose must stay line-coherent. The recoverable cost is
//   pass2: 183us for 280MB coalesced traffic (1.5TB/s) = latency-bound
//   (nt ws stores forced pass2 reads to HBM ~900cy; single-tile blocks have
//   nothing to hide it under; 50% LDS-capped occupancy).
//   Changes:
//    - pass1 ws stores: plain (ws fits L3 -> pass2 reads are L3 hits).
//      Pass1 is FETCH-invariant so L2 re-pollution is free.
//    - pass2: 4 tiles per block, software-pipelined: issue tile k+1 loads
//      BEFORE transposing/storing tile k (T14; applies because latency-bound
//      at 50% occupancy). Static reg indices (full unroll).
//   Predict: pass1 ~350us; pass2 183 -> ~90-120us; total ~440-470us.

#define NPTS     1000000
#define NLEV     16
#define TBL_ENT  524288      // 2^19 entries per level
#define BLK      256
#define OUT_PP   35          // floats per point
#define CHUNKS   ((NPTS + BLK - 1) / BLK)   // 3907
#define P2_TPB   4                               // tiles per pass2 block
#define P2GRID   ((CHUNKS + P2_TPB - 1) / P2_TPB)  // 977

// r:  16  22  30  42  58  80  111  153  212  294  406  561  776  1072 1482 2048
// hs: min(r^3, 2^19)
constexpr float    cRes[NLEV] = {16.f, 22.f, 30.f, 42.f, 58.f, 80.f, 111.f, 153.f,
                                 212.f, 294.f, 406.f, 561.f, 776.f, 1072.f, 1482.f, 2048.f};
constexpr uint32_t cHS[NLEV]  = {4096u, 10648u, 27000u, 74088u, 195112u, 512000u,
                                 524288u, 524288u, 524288u, 524288u, 524288u,
                                 524288u, 524288u, 524288u, 524288u, 524288u};

// ---------------- per-level gather (R2 form), compile-time level params ----------------

template<int L>
__device__ __forceinline__ void do_level(float px, float py, float pz,
                                         const float* __restrict__ tables,
                                         float& f0, float& f1)
{
    constexpr float    r  = cRes[L];
    constexpr uint32_t hs = cHS[L];
    const float2* __restrict__ tbl =
        reinterpret_cast<const float2*>(tables) + (size_t)L * TBL_ENT;

    const float xs = px * r, ys = py * r, zs = pz * r;
    const int xi = (int)xs, yi = (int)ys, zi = (int)zs;
    const float xf = xs - (float)xi, yf = ys - (float)yi, zf = zs - (float)zi;

    const uint32_t hx0 = (uint32_t)xi;
    const uint32_t hx1 = hx0 + 1u;
    const uint32_t hy0 = (uint32_t)yi * 2654435761u;
    const uint32_t hy1 = hy0 + 2654435761u;
    const uint32_t hz0 = (uint32_t)zi * 805459861u;
    const uint32_t hz1 = hz0 + 805459861u;

    const float wx0 = 1.f - xf, wx1 = xf;
    const float wy0 = 1.f - yf, wy1 = yf;
    const float wz0 = 1.f - zf, wz1 = zf;

    uint32_t hid[8];
    float    w[8];
    #pragma unroll
    for (int c = 0; c < 8; ++c) {
        const uint32_t hxc = (c & 1) ? hx1 : hx0;
        const uint32_t hyc = (c & 2) ? hy1 : hy0;
        const uint32_t hzc = (c & 4) ? hz1 : hz0;
        hid[c] = (hxc ^ hyc ^ hzc) % hs;   // hs compile-time: AND or magic-mul
        const float wxc = (c & 1) ? wx1 : wx0;
        const float wyc = (c & 2) ? wy1 : wy0;
        const float wzc = (c & 4) ? wz1 : wz0;
        w[c] = wxc * wyc * wzc;
    }

    float2 v[8];
    #pragma unroll
    for (int c = 0; c < 8; ++c) v[c] = tbl[hid[c]];

    f0 = 0.f; f1 = 0.f;
    #pragma unroll
    for (int c = 0; c < 8; ++c) {
        f0 = fmaf(w[c], v[c].x, f0);
        f1 = fmaf(w[c], v[c].y, f1);
    }
}

// ---------------- Pass 1: level-major gather ----------------

__global__ __launch_bounds__(BLK) void hashgrid_pass1(
    const float* __restrict__ x,
    const float* __restrict__ tables,
    float2* __restrict__ ws)
{
    const int b = blockIdx.x;
    const int l = b / CHUNKS;          // level (block-uniform)
    const int c = b - l * CHUNKS;      // point chunk
    const int i = c * BLK + threadIdx.x;
    if (i >= NPTS) return;

    // nt loads: no L1/L2 allocate; the active 4MB table keeps the XCD L2
    const float px = __builtin_nontemporal_load(&x[3 * i + 0]);
    const float py = __builtin_nontemporal_load(&x[3 * i + 1]);
    const float pz = __builtin_nontemporal_load(&x[3 * i + 2]);

    float f0, f1;
    switch (l) {
        case 0:  do_level<0 >(px, py, pz, tables, f0, f1); break;
        case 1:  do_level<1 >(px, py, pz, tables, f0, f1); break;
        case 2:  do_level<2 >(px, py, pz, tables, f0, f1); break;
        case 3:  do_level<3 >(px, py, pz, tables, f0, f1); break;
        case 4:  do_level<4 >(px, py, pz, tables, f0, f1); break;
        case 5:  do_level<5 >(px, py, pz, tables, f0, f1); break;
        case 6:  do_level<6 >(px, py, pz, tables, f0, f1); break;
        case 7:  do_level<7 >(px, py, pz, tables, f0, f1); break;
        case 8:  do_level<8 >(px, py, pz, tables, f0, f1); break;
        case 9:  do_level<9 >(px, py, pz, tables, f0, f1); break;
        case 10: do_level<10>(px, py, pz, tables, f0, f1); break;
        case 11: do_level<11>(px, py, pz, tables, f0, f1); break;
        case 12: do_level<12>(px, py, pz, tables, f0, f1); break;
        case 13: do_level<13>(px, py, pz, tables, f0, f1); break;
        case 14: do_level<14>(px, py, pz, tables, f0, f1); break;
        default: do_level<15>(px, py, pz, tables, f0, f1); break;
    }

    // PLAIN store (no nt): ws (128MB) stays L3-resident so pass2 reads are
    // L3 hits. Pass1 time is FETCH-invariant -> L2 pollution is free here.
    ws[(size_t)l * NPTS + i] = make_float2(f0, f1);
}

// ---------------- Pass 2: pipelined transpose ws (level-major) -> out (point-major) ----------------

__device__ __forceinline__ void load_row(const float* __restrict__ x,
                                         const float2* __restrict__ ws,
                                         int i, bool act, float (&r)[OUT_PP])
{
    if (act) {
        r[0] = x[3 * i + 0];
        r[1] = x[3 * i + 1];
        r[2] = x[3 * i + 2];
        #pragma unroll
        for (int l = 0; l < NLEV; ++l) {
            const float2 v = ws[(size_t)l * NPTS + i];   // coalesced 8B
            r[3 + 2 * l]     = v.x;
            r[4 + 2 * l]     = v.y;
        }
    }
}

__global__ __launch_bounds__(BLK) void hashgrid_pass2(
    const float* __restrict__ x,
    const float2* __restrict__ ws,
    float* __restrict__ out)
{
    __shared__ float smem[BLK * OUT_PP];   // 35840 B -> 4 blocks/CU

    const int t = threadIdx.x;
    const int tile0 = blockIdx.x * P2_TPB;

    float cur[OUT_PP], nxt[OUT_PP];

    // prologue: load tile0
    {
        const int i = tile0 * BLK + t;
        load_row(x, ws, i, (tile0 < CHUNKS) && (i < NPTS), cur);
    }

    #pragma unroll
    for (int k = 0; k < P2_TPB; ++k) {
        const int tile = tile0 + k;
        if (tile >= CHUNKS) break;               // block-uniform

        // 1) issue next tile's loads FIRST: their latency hides under this
        //    tile's LDS transpose + out stores (T14 async-stage split).
        {
            const int ntile = tile + 1;
            const bool hasN = (k + 1 < P2_TPB) && (ntile < CHUNKS);
            const int i = ntile * BLK + t;
            load_row(x, ws, i, hasN && (i < NPTS), nxt);
        }

        // 2) cur -> LDS (compiler waits only the older cur loads, counted vmcnt)
        {
            const int i = tile * BLK + t;
            if (i < NPTS) {
                #pragma unroll
                for (int q = 0; q < OUT_PP; ++q) smem[t * OUT_PP + q] = cur[q];
            }
        }
        __syncthreads();

        // 3) LDS -> out, coalesced float4
        {
            const size_t gbase = (size_t)tile * (BLK * OUT_PP);
            const long long remain = (long long)NPTS * OUT_PP - (long long)gbase;
            const int n4 = (int)((remain < (long long)(BLK * OUT_PP) ? remain : (long long)(BLK * OUT_PP)) / 4);
            const float4* __restrict__ s4 = reinterpret_cast<const float4*>(smem);
            float4* __restrict__ o4 = reinterpret_cast<float4*>(out + gbase);
            for (int j = t; j < n4; j += BLK) o4[j] = s4[j];
        }
        __syncthreads();                         // LDS reuse fence

        // 4) rotate registers (static indices)
        #pragma unroll
        for (int q = 0; q < OUT_PP; ++q) cur[q] = nxt[q];
    }
}

// ---------------- Fallback (point-major single kernel; used only if ws too small) ----------------

__global__ __launch_bounds__(BLK) void hashgrid_fused(
    const float* __restrict__ x,
    const float* __restrict__ tables,
    float* __restrict__ out)
{
    __shared__ float smem[BLK * OUT_PP];

    const int t = threadIdx.x;
    const int i = blockIdx.x * BLK + t;
    const bool active = (i < NPTS);

    float px = 0.f, py = 0.f, pz = 0.f;
    if (active) {
        px = x[3 * i + 0];
        py = x[3 * i + 1];
        pz = x[3 * i + 2];
    }
    smem[t * OUT_PP + 0] = px;
    smem[t * OUT_PP + 1] = py;
    smem[t * OUT_PP + 2] = pz;

    float f0, f1;
    #pragma unroll
    for (int l = 0; l < NLEV; ++l) {
        switch (l) {
            case 0:  do_level<0 >(px, py, pz, tables, f0, f1); break;
            case 1:  do_level<1 >(px, py, pz, tables, f0, f1); break;
            case 2:  do_level<2 >(px, py, pz, tables, f0, f1); break;
            case 3:  do_level<3 >(px, py, pz, tables, f0, f1); break;
            case 4:  do_level<4 >(px, py, pz, tables, f0, f1); break;
            case 5:  do_level<5 >(px, py, pz, tables, f0, f1); break;
            case 6:  do_level<6 >(px, py, pz, tables, f0, f1); break;
            case 7:  do_level<7 >(px, py, pz, tables, f0, f1); break;
            case 8:  do_level<8 >(px, py, pz, tables, f0, f1); break;
            case 9:  do_level<9 >(px, py, pz, tables, f0, f1); break;
            case 10: do_level<10>(px, py, pz, tables, f0, f1); break;
            case 11: do_level<11>(px, py, pz, tables, f0, f1); break;
            case 12: do_level<12>(px, py, pz, tables, f0, f1); break;
            case 13: do_level<13>(px, py, pz, tables, f0, f1); break;
            case 14: do_level<14>(px, py, pz, tables, f0, f1); break;
            default: do_level<15>(px, py, pz, tables, f0, f1); break;
        }
        smem[t * OUT_PP + 3 + 2 * l]     = f0;
        smem[t * OUT_PP + 3 + 2 * l + 1] = f1;
    }

    __syncthreads();

    const size_t gbase = (size_t)blockIdx.x * (BLK * OUT_PP);
    const long long remain = (long long)NPTS * OUT_PP - (long long)gbase;
    const int n4 = (int)((remain < (long long)(BLK * OUT_PP) ? remain : (long long)(BLK * OUT_PP)) / 4);
    const float4* __restrict__ s4 = reinterpret_cast<const float4*>(smem);
    float4* __restrict__ o4 = reinterpret_cast<float4*>(out + gbase);
    for (int j = t; j < n4; j += BLK) o4[j] = s4[j];
}

extern "C" void kernel_launch(void* const* d_in, const int* in_sizes, int n_in,
                              void* d_out, int out_size, void* d_ws, size_t ws_size,
                              hipStream_t stream)
{
    const float* x      = (const float*)d_in[0];   // (1e6, 3) f32
    const float* tables = (const float*)d_in[1];   // (16, 2^19, 2) f32
    float* out          = (float*)d_out;           // (1e6, 35) f32

    const size_t ws_needed = (size_t)NLEV * NPTS * sizeof(float2);   // 128 MB

    if (ws_size >= ws_needed) {
        float2* ws = (float2*)d_ws;
        hashgrid_pass1<<<NLEV * CHUNKS, BLK, 0, stream>>>(x, tables, ws);
        hashgrid_pass2<<<P2GRID, BLK, 0, stream>>>(x, ws, out);
    } else {
        hashgrid_fused<<<CHUNKS, BLK, 0, stream>>>(x, tables, out);
    }
}